// Round 1
// baseline (136.178 us; speedup 1.0000x reference)
//
#include <hip/hip_runtime.h>
#include <math.h>

// Problem constants (match reference)
#define BATCH   2048
#define IN_DIM  4096
#define OUT_DIM 1024
#define N_EDGES 16384

#define NT 8  // nodes per block in main kernel

// ---------------------------------------------------------------------------
// Kernel 1: node offsets via binary search over sorted edge_dst
// node_off[o] = lower_bound(edge_dst, o); edges of node n = [off[n], off[n+1])
// ---------------------------------------------------------------------------
__global__ void offsets_kernel(const int* __restrict__ edge_dst,
                               int* __restrict__ node_off) {
    int o = blockIdx.x * blockDim.x + threadIdx.x;
    if (o > OUT_DIM) return;
    int lo = 0, hi = N_EDGES;
    while (lo < hi) {
        int mid = (lo + hi) >> 1;
        if (edge_dst[mid] < o) lo = mid + 1; else hi = mid;
    }
    node_off[o] = lo;
}

// ---------------------------------------------------------------------------
// Kernel 2: transpose x [BATCH][IN_DIM] -> xT [IN_DIM][BATCH] (fp32)
// 32x32 LDS tile, +1 pad. Block (32,8), each thread moves 4 elements.
// ---------------------------------------------------------------------------
#define TDIM 32
__global__ __launch_bounds__(256) void transpose_kernel(
        const float* __restrict__ x, float* __restrict__ xT) {
    __shared__ float tile[TDIM][TDIM + 1];
    const int bx = blockIdx.x * TDIM;  // column base in x (IN_DIM axis)
    const int by = blockIdx.y * TDIM;  // row base in x (BATCH axis)
    const int tx = threadIdx.x, ty = threadIdx.y;
#pragma unroll
    for (int j = 0; j < TDIM; j += 8)
        tile[ty + j][tx] = x[(size_t)(by + ty + j) * IN_DIM + bx + tx];
    __syncthreads();
#pragma unroll
    for (int j = 0; j < TDIM; j += 8)
        xT[(size_t)(bx + ty + j) * BATCH + by + tx] = tile[tx][ty + j];
}

// ---------------------------------------------------------------------------
// Kernel 3: main gather/reduce.
// Block: 256 threads = one batch tile of 256; covers NT consecutive nodes.
// grid = (OUT_DIM/NT, BATCH/256). Per-edge: uniform scalar loads of
// src/weight, one coalesced 1KB row read from xT. Epilogue: sigmoid(tanh()).
// Store: NT consecutive floats per thread (2x float4), write-combining.
// ---------------------------------------------------------------------------
__global__ __launch_bounds__(256) void gather_kernel(
        const float* __restrict__ xT,
        const int* __restrict__ edge_src,
        const float* __restrict__ weights,
        const int* __restrict__ node_off,
        float* __restrict__ out) {
    const int node_base = blockIdx.x * NT;
    const int b = blockIdx.y * 256 + threadIdx.x;

    float acc[NT];
#pragma unroll
    for (int n = 0; n < NT; n++) acc[n] = 0.0f;

#pragma unroll
    for (int n = 0; n < NT; n++) {
        const int lo = node_off[node_base + n];
        const int hi = node_off[node_base + n + 1];
        for (int e = lo; e < hi; e++) {
            const int s  = edge_src[e];   // uniform -> scalar load
            const float w = weights[e];   // uniform -> scalar load
            acc[n] += w * xT[(size_t)s * BATCH + b];  // coalesced
        }
    }

    float vals[NT];
#pragma unroll
    for (int n = 0; n < NT; n++) {
        const float h = tanhf(acc[n]);
        vals[n] = 1.0f / (1.0f + expf(-h));
    }

    float4* o4 = (float4*)(out + (size_t)b * OUT_DIM + node_base);
#pragma unroll
    for (int n = 0; n < NT / 4; n++)
        o4[n] = make_float4(vals[4 * n], vals[4 * n + 1],
                            vals[4 * n + 2], vals[4 * n + 3]);
}

// ---------------------------------------------------------------------------
extern "C" void kernel_launch(void* const* d_in, const int* in_sizes, int n_in,
                              void* d_out, int out_size, void* d_ws, size_t ws_size,
                              hipStream_t stream) {
    const float* x        = (const float*)d_in[0];  // [BATCH, IN_DIM]
    const float* weights  = (const float*)d_in[1];  // [N_EDGES]
    const int*   edge_src = (const int*)d_in[2];    // [N_EDGES]
    const int*   edge_dst = (const int*)d_in[3];    // [N_EDGES] sorted
    float*       out      = (float*)d_out;          // [BATCH, OUT_DIM]

    // ws layout: xT (IN_DIM*BATCH fp32 = 32 MiB) | node_off (1025 ints)
    float* xT      = (float*)d_ws;
    int*   node_off = (int*)((char*)d_ws + (size_t)IN_DIM * BATCH * sizeof(float));

    // 1. per-node edge offsets (independent of transpose)
    offsets_kernel<<<(OUT_DIM + 1 + 255) / 256, 256, 0, stream>>>(edge_dst, node_off);

    // 2. transpose x -> xT
    dim3 tgrid(IN_DIM / TDIM, BATCH / TDIM);
    dim3 tblock(TDIM, 8);
    transpose_kernel<<<tgrid, tblock, 0, stream>>>(x, xT);

    // 3. main gather/reduce/activation
    dim3 ggrid(OUT_DIM / NT, BATCH / 256);
    gather_kernel<<<ggrid, 256, 0, stream>>>(xT, edge_src, weights, node_off, out);
}

// Round 2
// 101.884 us; speedup vs baseline: 1.3366x; 1.3366x over previous
//
#include <hip/hip_runtime.h>
#include <math.h>

// Problem constants (match reference)
#define BATCH   2048
#define IN_DIM  4096
#define OUT_DIM 1024
#define N_EDGES 16384

#define R   2   // batch rows per block (LDS = R*16KB)
#define NPT 4   // nodes per thread (256 threads * 4 = 1024 = OUT_DIM)

// ---------------------------------------------------------------------------
// Prep kernel: (a) node offsets via binary search over sorted edge_dst,
//              (b) pack (edge_src, weight) into int2 for single-load access.
// ---------------------------------------------------------------------------
__global__ __launch_bounds__(256) void prep_kernel(
        const int* __restrict__ edge_dst,
        const int* __restrict__ edge_src,
        const float* __restrict__ weights,
        int* __restrict__ node_off,
        int2* __restrict__ epack) {
    const int i = blockIdx.x * 256 + threadIdx.x;
    if (i < N_EDGES)
        epack[i] = make_int2(edge_src[i], __float_as_int(weights[i]));
    if (i <= OUT_DIM) {
        int lo = 0, hi = N_EDGES;
        while (lo < hi) {
            int mid = (lo + hi) >> 1;
            if (edge_dst[mid] < i) lo = mid + 1; else hi = mid;
        }
        node_off[i] = lo;
    }
}

// ---------------------------------------------------------------------------
// Fused kernel: block = 256 threads, handles R batch rows x ALL 1024 nodes.
// 1. Stage R rows of x into LDS with coalesced float4 loads (compulsory-only
//    HBM traffic for x: 32 MB total, no transpose kernel needed).
// 2. Each thread owns NPT consecutive nodes; per edge: one 8B L2-hot load of
//    (src,w), LDS gather (random bank ~2-way = free), FMA into registers.
// 3. sigmoid(tanh()) epilogue, float4 coalesced stores.
// ---------------------------------------------------------------------------
__global__ __launch_bounds__(256) void fused_kernel(
        const float* __restrict__ x,
        const int2* __restrict__ epack,
        const int* __restrict__ node_off,
        float* __restrict__ out) {
    __shared__ float xs[R * IN_DIM];  // 32 KB

    const int brow = blockIdx.x * R;

    // --- stage R contiguous rows of x into LDS (float4, fully coalesced) ---
    const float4* src4 = (const float4*)(x + (size_t)brow * IN_DIM);
    float4* xs4 = (float4*)xs;
#pragma unroll
    for (int i = 0; i < (R * IN_DIM / 4) / 256; i++)
        xs4[threadIdx.x + i * 256] = src4[threadIdx.x + i * 256];
    __syncthreads();

    // --- per-thread node spans ---
    const int node0 = threadIdx.x * NPT;
    const int4 o4 = *(const int4*)(node_off + node0);
    const int oend = node_off[node0 + NPT];
    const int lo[NPT + 1] = {o4.x, o4.y, o4.z, o4.w, oend};

    float v0[NPT], v1[NPT];
#pragma unroll
    for (int n = 0; n < NPT; n++) {
        float a0 = 0.0f, a1 = 0.0f;
#pragma unroll 4
        for (int e = lo[n]; e < lo[n + 1]; e++) {
            const int2 p = epack[e];
            const float w = __int_as_float(p.y);
            a0 = fmaf(w, xs[p.x], a0);
            a1 = fmaf(w, xs[IN_DIM + p.x], a1);
        }
        const float h0 = tanhf(a0);
        const float h1 = tanhf(a1);
        v0[n] = 1.0f / (1.0f + expf(-h0));
        v1[n] = 1.0f / (1.0f + expf(-h1));
    }

    // --- coalesced float4 stores ---
    *(float4*)(out + (size_t)(brow + 0) * OUT_DIM + node0) =
        make_float4(v0[0], v0[1], v0[2], v0[3]);
    *(float4*)(out + (size_t)(brow + 1) * OUT_DIM + node0) =
        make_float4(v1[0], v1[1], v1[2], v1[3]);
}

// ---------------------------------------------------------------------------
extern "C" void kernel_launch(void* const* d_in, const int* in_sizes, int n_in,
                              void* d_out, int out_size, void* d_ws, size_t ws_size,
                              hipStream_t stream) {
    const float* x        = (const float*)d_in[0];  // [BATCH, IN_DIM]
    const float* weights  = (const float*)d_in[1];  // [N_EDGES]
    const int*   edge_src = (const int*)d_in[2];    // [N_EDGES]
    const int*   edge_dst = (const int*)d_in[3];    // [N_EDGES] sorted
    float*       out      = (float*)d_out;          // [BATCH, OUT_DIM]

    // ws layout: node_off (1025 ints, padded to 8KB) | epack (N_EDGES int2)
    int*  node_off = (int*)d_ws;
    int2* epack    = (int2*)((char*)d_ws + 8192);

    prep_kernel<<<N_EDGES / 256, 256, 0, stream>>>(
        edge_dst, edge_src, weights, node_off, epack);

    fused_kernel<<<BATCH / R, 256, 0, stream>>>(x, epack, node_off, out);
}